// Round 2
// baseline (10582.194 us; speedup 1.0000x reference)
//
#include <hip/hip_runtime.h>
#include <stdint.h>

typedef unsigned short u16;
typedef __bf16 bf16x8 __attribute__((ext_vector_type(8)));
typedef u16    u16x8  __attribute__((ext_vector_type(8)));
typedef float  f32x4  __attribute__((ext_vector_type(4)));

#define TSTEPS 100
#define BATCH  256
#define INDIM  700
#define HID    2048
#define ODIM   20

#define KS_IN  22            // ceil(700/32)
#define KS_HID 64            // 2048/32
#define JT_HID 128           // 2048/16
#define PS_IN  ((size_t)JT_HID*KS_IN*512)    // elems per plane (L0)
#define PS_HID ((size_t)JT_HID*KS_HID*512)   // elems per plane (hidden)
#define PS_OUT ((size_t)2*KS_HID*512)        // elems per plane (L4, N padded to 32)

__device__ __forceinline__ bf16x8 ldb8(const u16* p) {
  return *reinterpret_cast<const bf16x8*>(p);
}

__device__ __forceinline__ f32x4 mf(bf16x8 a, bf16x8 b, f32x4 c) {
  return __builtin_amdgcn_mfma_f32_16x16x32_bf16(a, b, c, 0, 0, 0);
}

// ------------------------------ init ------------------------------
__global__ void k_zero(float4* __restrict__ p, int n4) {
  int i = blockIdx.x * 256 + threadIdx.x;
  int s = gridDim.x * 256;
  float4 z; z.x = 0.f; z.y = 0.f; z.z = 0.f; z.w = 0.f;
  for (; i < n4; i += s) p[i] = z;
}

// -------------------- weight split into fragment layout --------------------
// chunk c = (jt*KS + ks)*64 + lane ; elem e of chunk holds
//   plane_p( W[jt*16 + (lane&15)][ks*32 + (lane>>4)*8 + e] )
// so a wave's B-fragment load is one coalesced 16B/lane read.
__global__ void k_split(const float* __restrict__ W, u16* __restrict__ outp,
                        int N, int K, int KS, int nchunks, int planes, size_t ps) {
  int c = blockIdx.x * 256 + threadIdx.x;
  if (c >= nchunks) return;
  int lane = c & 63;
  int t  = c >> 6;
  int ks = t % KS;
  int jt = t / KS;
  int j  = jt * 16 + (lane & 15);
  int k0 = ks * 32 + ((lane >> 4) << 3);
  float x[8];
  if (j < N) {
    const float* wr = W + (size_t)j * K;
    if (k0 + 7 < K) {
      float4 v0 = *reinterpret_cast<const float4*>(wr + k0);
      float4 v1 = *reinterpret_cast<const float4*>(wr + k0 + 4);
      x[0]=v0.x; x[1]=v0.y; x[2]=v0.z; x[3]=v0.w;
      x[4]=v1.x; x[5]=v1.y; x[6]=v1.z; x[7]=v1.w;
    } else {
      #pragma unroll
      for (int e = 0; e < 8; e++) x[e] = (k0 + e < K) ? wr[k0 + e] : 0.0f;
    }
  } else {
    #pragma unroll
    for (int e = 0; e < 8; e++) x[e] = 0.0f;
  }
  u16x8 vh, vm, vl;
  #pragma unroll
  for (int e = 0; e < 8; e++) {
    float w   = x[e];
    __bf16 bh = (__bf16)w;            // RNE
    float r1  = w - (float)bh;        // exact (Sterbenz-ish; bh has >= w's exponent range)
    __bf16 bm = (__bf16)r1;
    __bf16 bl = (__bf16)(r1 - (float)bm);
    vh[e] = __builtin_bit_cast(unsigned short, bh);
    vm[e] = __builtin_bit_cast(unsigned short, bm);
    vl[e] = __builtin_bit_cast(unsigned short, bl);
  }
  size_t base = (size_t)c * 8;
  *reinterpret_cast<u16x8*>(outp + base) = vh;
  if (planes > 1) *reinterpret_cast<u16x8*>(outp + ps     + base) = vm;
  if (planes > 2) *reinterpret_cast<u16x8*>(outp + 2 * ps + base) = vl;
}

// ------------------------------ LIF ------------------------------
__device__ __forceinline__ void lif_store(float cur, float* __restrict__ mem,
                                          size_t idx, u16* __restrict__ spk) {
  float mo = mem[idx];
  float mn = 0.9f * mo + cur - ((mo > 1.0f) ? 1.0f : 0.0f);
  mem[idx] = mn;
  spk[idx] = (mn - 1.0f > 0.0f) ? (u16)0x3F80 : (u16)0;   // bf16 1.0 / 0.0 (exact)
}

// --------------------------- hidden layer ---------------------------
// grid 256 = 4 mt x 64 nt (XCD = nt%8 pins W n-slices to one XCD's L2).
// 8 waves: (jf, mfh, kh) — kh splits K; LDS-reduce at the end.
// Per wave: 2-pair-deep pipeline (U/V), 4 accumulator chains.
template<int P>
__global__ __launch_bounds__(512) void k_hid(
    const u16* __restrict__ A, const u16* __restrict__ Wf,
    const float* __restrict__ bias, float* __restrict__ mem,
    u16* __restrict__ spk_out) {
  __shared__ float red[4][512];
  int mt = blockIdx.x >> 6, nt = blockIdx.x & 63;
  int wid = threadIdx.x >> 6, lane = threadIdx.x & 63;
  int r15 = lane & 15, g = lane >> 4;
  int jf = wid & 1, mfh = (wid >> 1) & 1, kh = wid >> 2;
  const int ksb = kh * (KS_HID / 2);
  const int np  = KS_HID / 4;                 // 16 pairs per half

  const u16* wb = Wf + ((size_t)(nt * 2 + jf) * KS_HID) * 512 + (size_t)lane * 8;
  const u16* a0 = A + (size_t)(mt * 64 + mfh * 32 + r15) * HID + g * 8;
  const u16* a1 = a0 + 16 * HID;

  f32x4 c0a{}, c1a{}, c0b{}, c1b{};
  bf16x8 wU0[P], wU1[P], wV0[P], wV1[P];
  bf16x8 aU00, aU01, aU10, aU11, aV00, aV01, aV10, aV11;

  auto loadU = [&](int pr) {
    int k0 = ksb + pr * 2;
    #pragma unroll
    for (int p = 0; p < P; p++) {
      wU0[p] = ldb8(wb + (size_t)p * PS_HID + (size_t)k0 * 512);
      wU1[p] = ldb8(wb + (size_t)p * PS_HID + (size_t)(k0 + 1) * 512);
    }
    aU00 = ldb8(a0 + k0 * 32);       aU10 = ldb8(a1 + k0 * 32);
    aU01 = ldb8(a0 + (k0 + 1) * 32); aU11 = ldb8(a1 + (k0 + 1) * 32);
  };
  auto loadV = [&](int pr) {
    int k0 = ksb + pr * 2;
    #pragma unroll
    for (int p = 0; p < P; p++) {
      wV0[p] = ldb8(wb + (size_t)p * PS_HID + (size_t)k0 * 512);
      wV1[p] = ldb8(wb + (size_t)p * PS_HID + (size_t)(k0 + 1) * 512);
    }
    aV00 = ldb8(a0 + k0 * 32);       aV10 = ldb8(a1 + k0 * 32);
    aV01 = ldb8(a0 + (k0 + 1) * 32); aV11 = ldb8(a1 + (k0 + 1) * 32);
  };
  auto compU = [&]() {
    #pragma unroll
    for (int p = 0; p < P; p++) {
      c0a = mf(aU00, wU0[p], c0a); c1a = mf(aU10, wU0[p], c1a);
      c0b = mf(aU01, wU1[p], c0b); c1b = mf(aU11, wU1[p], c1b);
    }
  };
  auto compV = [&]() {
    #pragma unroll
    for (int p = 0; p < P; p++) {
      c0a = mf(aV00, wV0[p], c0a); c1a = mf(aV10, wV0[p], c1a);
      c0b = mf(aV01, wV1[p], c0b); c1b = mf(aV11, wV1[p], c1b);
    }
  };

  loadU(0);
  loadV(1);
  int i = 0;
  for (; i + 2 < np; i += 2) {
    compU(); loadU(i + 2);
    compV(); if (i + 3 < np) loadV(i + 3);
  }
  compU();
  if (i + 1 < np) compV();

  f32x4 acc0 = c0a + c0b, acc1 = c1a + c1b;

  if (kh == 1) {
    #pragma unroll
    for (int r = 0; r < 4; r++) {
      red[wid - 4][lane * 8 + r]     = acc0[r];
      red[wid - 4][lane * 8 + 4 + r] = acc1[r];
    }
  }
  __syncthreads();
  if (kh == 0) {
    int jc = nt * 32 + jf * 16 + r15;
    float bj = bias[jc];
    #pragma unroll
    for (int r = 0; r < 4; r++) {
      float v0 = acc0[r] + red[wid][lane * 8 + r]     + bj;
      float v1 = acc1[r] + red[wid][lane * 8 + 4 + r] + bj;
      int br0 = mt * 64 + mfh * 32 + g * 4 + r;        // C/D: row=(lane>>4)*4+r, col=lane&15
      lif_store(v0, mem, (size_t)br0 * HID + jc, spk_out);
      lif_store(v1, mem, (size_t)(br0 + 16) * HID + jc, spk_out);
    }
  }
}

// --------------------------- input layer ---------------------------
__device__ __forceinline__ void load_split(const float* __restrict__ ar, int k0,
                                           bf16x8& dh, bf16x8& dl) {
  float x[8];
  if (k0 + 7 < INDIM) {
    float4 v0 = *reinterpret_cast<const float4*>(ar + k0);
    float4 v1 = *reinterpret_cast<const float4*>(ar + k0 + 4);
    x[0]=v0.x; x[1]=v0.y; x[2]=v0.z; x[3]=v0.w;
    x[4]=v1.x; x[5]=v1.y; x[6]=v1.z; x[7]=v1.w;
  } else {
    #pragma unroll
    for (int e = 0; e < 8; e++) x[e] = (k0 + e < INDIM) ? ar[k0 + e] : 0.0f;
  }
  #pragma unroll
  for (int e = 0; e < 8; e++) {
    __bf16 h = (__bf16)x[e];
    dh[e] = h;
    dl[e] = (__bf16)(x[e] - (float)h);
  }
}

template<int P>
__global__ __launch_bounds__(512) void k_in(
    const float* __restrict__ A, const u16* __restrict__ Wf,
    const float* __restrict__ bias, float* __restrict__ mem,
    u16* __restrict__ spk_out) {
  constexpr int PL = (P < 3) ? P : 2;   // dl pairs with wh,wm only (dl*wl <= 2^-27)
  __shared__ float red[4][512];
  int mt = blockIdx.x >> 6, nt = blockIdx.x & 63;
  int wid = threadIdx.x >> 6, lane = threadIdx.x & 63;
  int r15 = lane & 15, g = lane >> 4;
  int jf = wid & 1, mfh = (wid >> 1) & 1, kh = wid >> 2;
  const int ksb = kh ? 12 : 0;          // K halves: 12 + 10 k-steps (pairs whole)
  const int np  = kh ? 5 : 6;

  const u16* wb = Wf + ((size_t)(nt * 2 + jf) * KS_IN) * 512 + (size_t)lane * 8;
  const float* a0 = A + (size_t)(mt * 64 + mfh * 32 + r15) * INDIM;
  const float* a1 = a0 + 16 * INDIM;

  f32x4 c0a{}, c1a{}, c0b{}, c1b{};
  bf16x8 wU0[P], wU1[P], wV0[P], wV1[P];
  bf16x8 hU00, hU01, hU10, hU11, lU00, lU01, lU10, lU11;
  bf16x8 hV00, hV01, hV10, hV11, lV00, lV01, lV10, lV11;

  auto loadU = [&](int pr) {
    int ks = ksb + pr * 2;
    int k0 = ks * 32 + g * 8;
    #pragma unroll
    for (int p = 0; p < P; p++) {
      wU0[p] = ldb8(wb + (size_t)p * PS_IN + (size_t)ks * 512);
      wU1[p] = ldb8(wb + (size_t)p * PS_IN + (size_t)(ks + 1) * 512);
    }
    load_split(a0, k0, hU00, lU00);      load_split(a1, k0, hU10, lU10);
    load_split(a0, k0 + 32, hU01, lU01); load_split(a1, k0 + 32, hU11, lU11);
  };
  auto loadV = [&](int pr) {
    int ks = ksb + pr * 2;
    int k0 = ks * 32 + g * 8;
    #pragma unroll
    for (int p = 0; p < P; p++) {
      wV0[p] = ldb8(wb + (size_t)p * PS_IN + (size_t)ks * 512);
      wV1[p] = ldb8(wb + (size_t)p * PS_IN + (size_t)(ks + 1) * 512);
    }
    load_split(a0, k0, hV00, lV00);      load_split(a1, k0, hV10, lV10);
    load_split(a0, k0 + 32, hV01, lV01); load_split(a1, k0 + 32, hV11, lV11);
  };
  auto compU = [&]() {
    #pragma unroll
    for (int p = 0; p < P; p++) {
      c0a = mf(hU00, wU0[p], c0a); c1a = mf(hU10, wU0[p], c1a);
      c0b = mf(hU01, wU1[p], c0b); c1b = mf(hU11, wU1[p], c1b);
    }
    #pragma unroll
    for (int p = 0; p < PL; p++) {
      c0a = mf(lU00, wU0[p], c0a); c1a = mf(lU10, wU0[p], c1a);
      c0b = mf(lU01, wU1[p], c0b); c1b = mf(lU11, wU1[p], c1b);
    }
  };
  auto compV = [&]() {
    #pragma unroll
    for (int p = 0; p < P; p++) {
      c0a = mf(hV00, wV0[p], c0a); c1a = mf(hV10, wV0[p], c1a);
      c0b = mf(hV01, wV1[p], c0b); c1b = mf(hV11, wV1[p], c1b);
    }
    #pragma unroll
    for (int p = 0; p < PL; p++) {
      c0a = mf(lV00, wV0[p], c0a); c1a = mf(lV10, wV0[p], c1a);
      c0b = mf(lV01, wV1[p], c0b); c1b = mf(lV11, wV1[p], c1b);
    }
  };

  loadU(0);
  if (np > 1) loadV(1);
  int i = 0;
  for (; i + 2 < np; i += 2) {
    compU(); loadU(i + 2);
    compV(); if (i + 3 < np) loadV(i + 3);
  }
  compU();
  if (i + 1 < np) compV();

  f32x4 acc0 = c0a + c0b, acc1 = c1a + c1b;

  if (kh == 1) {
    #pragma unroll
    for (int r = 0; r < 4; r++) {
      red[wid - 4][lane * 8 + r]     = acc0[r];
      red[wid - 4][lane * 8 + 4 + r] = acc1[r];
    }
  }
  __syncthreads();
  if (kh == 0) {
    int jc = nt * 32 + jf * 16 + r15;
    float bj = bias[jc];
    #pragma unroll
    for (int r = 0; r < 4; r++) {
      float v0 = acc0[r] + red[wid][lane * 8 + r]     + bj;
      float v1 = acc1[r] + red[wid][lane * 8 + 4 + r] + bj;
      int br0 = mt * 64 + mfh * 32 + g * 4 + r;
      lif_store(v0, mem, (size_t)br0 * HID + jc, spk_out);
      lif_store(v1, mem, (size_t)(br0 + 16) * HID + jc, spk_out);
    }
  }
}

// --------------------------- output layer ---------------------------
template<int P>
__global__ __launch_bounds__(512) void k_out(
    const u16* __restrict__ A, const u16* __restrict__ Wf,
    const float* __restrict__ bias, float* __restrict__ mem4,
    float* __restrict__ outp) {
  __shared__ float red[4][512];
  int mt = blockIdx.x;                       // 0..3
  int wid = threadIdx.x >> 6, lane = threadIdx.x & 63;
  int r15 = lane & 15, g = lane >> 4;
  int jf = wid & 1, mfh = (wid >> 1) & 1, kh = wid >> 2;
  const int ksb = kh * (KS_HID / 2);
  const int np  = KS_HID / 4;

  const u16* wb = Wf + ((size_t)jf * KS_HID) * 512 + (size_t)lane * 8;
  const u16* a0 = A + (size_t)(mt * 64 + mfh * 32 + r15) * HID + g * 8;
  const u16* a1 = a0 + 16 * HID;

  f32x4 c0a{}, c1a{}, c0b{}, c1b{};
  bf16x8 wU0[P], wU1[P], wV0[P], wV1[P];
  bf16x8 aU00, aU01, aU10, aU11, aV00, aV01, aV10, aV11;

  auto loadU = [&](int pr) {
    int k0 = ksb + pr * 2;
    #pragma unroll
    for (int p = 0; p < P; p++) {
      wU0[p] = ldb8(wb + (size_t)p * PS_OUT + (size_t)k0 * 512);
      wU1[p] = ldb8(wb + (size_t)p * PS_OUT + (size_t)(k0 + 1) * 512);
    }
    aU00 = ldb8(a0 + k0 * 32);       aU10 = ldb8(a1 + k0 * 32);
    aU01 = ldb8(a0 + (k0 + 1) * 32); aU11 = ldb8(a1 + (k0 + 1) * 32);
  };
  auto loadV = [&](int pr) {
    int k0 = ksb + pr * 2;
    #pragma unroll
    for (int p = 0; p < P; p++) {
      wV0[p] = ldb8(wb + (size_t)p * PS_OUT + (size_t)k0 * 512);
      wV1[p] = ldb8(wb + (size_t)p * PS_OUT + (size_t)(k0 + 1) * 512);
    }
    aV00 = ldb8(a0 + k0 * 32);       aV10 = ldb8(a1 + k0 * 32);
    aV01 = ldb8(a0 + (k0 + 1) * 32); aV11 = ldb8(a1 + (k0 + 1) * 32);
  };
  auto compU = [&]() {
    #pragma unroll
    for (int p = 0; p < P; p++) {
      c0a = mf(aU00, wU0[p], c0a); c1a = mf(aU10, wU0[p], c1a);
      c0b = mf(aU01, wU1[p], c0b); c1b = mf(aU11, wU1[p], c1b);
    }
  };
  auto compV = [&]() {
    #pragma unroll
    for (int p = 0; p < P; p++) {
      c0a = mf(aV00, wV0[p], c0a); c1a = mf(aV10, wV0[p], c1a);
      c0b = mf(aV01, wV1[p], c0b); c1b = mf(aV11, wV1[p], c1b);
    }
  };

  loadU(0);
  loadV(1);
  int i = 0;
  for (; i + 2 < np; i += 2) {
    compU(); loadU(i + 2);
    compV(); if (i + 3 < np) loadV(i + 3);
  }
  compU();
  if (i + 1 < np) compV();

  f32x4 acc0 = c0a + c0b, acc1 = c1a + c1b;

  if (kh == 1) {
    #pragma unroll
    for (int r = 0; r < 4; r++) {
      red[wid - 4][lane * 8 + r]     = acc0[r];
      red[wid - 4][lane * 8 + 4 + r] = acc1[r];
    }
  }
  __syncthreads();
  if (kh == 0) {
    int jc = jf * 16 + r15;                  // 0..31 (N padded)
    float bj = (jc < ODIM) ? bias[jc] : 0.0f;
    #pragma unroll
    for (int r = 0; r < 4; r++) {
      float v0 = acc0[r] + red[wid][lane * 8 + r]     + bj;
      float v1 = acc1[r] + red[wid][lane * 8 + 4 + r] + bj;
      int br0 = mt * 64 + mfh * 32 + g * 4 + r;
      #pragma unroll
      for (int m = 0; m < 2; m++) {
        float cur = m ? v1 : v0;
        int br = br0 + m * 16;
        size_t midx = (size_t)br * 32 + jc;
        float mo = mem4[midx];
        float mn = 0.9f * mo + cur - ((mo > 1.0f) ? 1.0f : 0.0f);
        mem4[midx] = mn;
        if (jc < ODIM) outp[(size_t)br * ODIM + jc] = (mn - 1.0f > 0.0f) ? 1.0f : 0.0f;
      }
    }
  }
}

// ------------------------------ host ------------------------------
struct Ptrs {
  float *mem0, *mem1, *mem2, *mem3, *mem4;
  u16 *spk0, *spk1, *spk2, *spk3;
  u16 *w0, *w1, *w2, *w3, *w4;
};

template<int P>
static void launch_all(const float* data,
                       const float* W0, const float* b0, const float* W1, const float* b1,
                       const float* W2, const float* b2, const float* W3, const float* b3,
                       const float* W4, const float* b4,
                       float* out, const Ptrs& q, hipStream_t s) {
  int n4 = (4 * BATCH * HID + BATCH * 32) / 4;
  k_zero<<<dim3(1024), dim3(256), 0, s>>>((float4*)q.mem0, n4);

  int nc0 = JT_HID * KS_IN * 64;
  k_split<<<dim3(nc0 / 256), dim3(256), 0, s>>>(W0, q.w0, HID, INDIM, KS_IN, nc0, P, PS_IN);
  int nch = JT_HID * KS_HID * 64;
  k_split<<<dim3(nch / 256), dim3(256), 0, s>>>(W1, q.w1, HID, HID, KS_HID, nch, P, PS_HID);
  k_split<<<dim3(nch / 256), dim3(256), 0, s>>>(W2, q.w2, HID, HID, KS_HID, nch, P, PS_HID);
  k_split<<<dim3(nch / 256), dim3(256), 0, s>>>(W3, q.w3, HID, HID, KS_HID, nch, P, PS_HID);
  int nc4 = 2 * KS_HID * 64;
  k_split<<<dim3(nc4 / 256), dim3(256), 0, s>>>(W4, q.w4, ODIM, HID, KS_HID, nc4, P, PS_OUT);

  for (int t = 0; t < TSTEPS; t++) {
    k_in<P> <<<dim3(256), dim3(512), 0, s>>>(data + (size_t)t * BATCH * INDIM, q.w0, b0, q.mem0, q.spk0);
    k_hid<P><<<dim3(256), dim3(512), 0, s>>>(q.spk0, q.w1, b1, q.mem1, q.spk1);
    k_hid<P><<<dim3(256), dim3(512), 0, s>>>(q.spk1, q.w2, b2, q.mem2, q.spk2);
    k_hid<P><<<dim3(256), dim3(512), 0, s>>>(q.spk2, q.w3, b3, q.mem3, q.spk3);
    k_out<P><<<dim3(4),   dim3(512), 0, s>>>(q.spk3, q.w4, b4, q.mem4, out + (size_t)t * BATCH * ODIM);
  }
}

extern "C" void kernel_launch(void* const* d_in, const int* in_sizes, int n_in,
                              void* d_out, int out_size, void* d_ws, size_t ws_size,
                              hipStream_t stream) {
  (void)in_sizes; (void)n_in; (void)out_size;
  const float* data = (const float*)d_in[0];
  const float* W0 = (const float*)d_in[1];  const float* b0 = (const float*)d_in[2];
  const float* W1 = (const float*)d_in[3];  const float* b1 = (const float*)d_in[4];
  const float* W2 = (const float*)d_in[5];  const float* b2 = (const float*)d_in[6];
  const float* W3 = (const float*)d_in[7];  const float* b3 = (const float*)d_in[8];
  const float* W4 = (const float*)d_in[9];  const float* b4 = (const float*)d_in[10];
  float* out = (float*)d_out;

  uint8_t* ws = (uint8_t*)d_ws;
  size_t off = 0;
  auto take = [&](size_t bytes) -> uint8_t* { uint8_t* r = ws + off; off += bytes; return r; };

  Ptrs q;
  q.mem0 = (float*)take((size_t)BATCH * HID * 4);
  q.mem1 = (float*)take((size_t)BATCH * HID * 4);
  q.mem2 = (float*)take((size_t)BATCH * HID * 4);
  q.mem3 = (float*)take((size_t)BATCH * HID * 4);
  q.mem4 = (float*)take((size_t)BATCH * 32 * 4);
  q.spk0 = (u16*)take((size_t)BATCH * HID * 2);
  q.spk1 = (u16*)take((size_t)BATCH * HID * 2);
  q.spk2 = (u16*)take((size_t)BATCH * HID * 2);
  q.spk3 = (u16*)take((size_t)BATCH * HID * 2);

  size_t fixed = off;
  size_t per_set = 2 * (PS_IN + 3 * PS_HID + PS_OUT);   // bytes per plane-set
  int P = 3;
  if (fixed + 3 * per_set > ws_size) P = 2;
  if (fixed + 2 * per_set > ws_size) P = 1;

  q.w0 = (u16*)take((size_t)P * PS_IN * 2);
  q.w1 = (u16*)take((size_t)P * PS_HID * 2);
  q.w2 = (u16*)take((size_t)P * PS_HID * 2);
  q.w3 = (u16*)take((size_t)P * PS_HID * 2);
  q.w4 = (u16*)take((size_t)P * PS_OUT * 2);

  if (P == 3)      launch_all<3>(data, W0,b0, W1,b1, W2,b2, W3,b3, W4,b4, out, q, stream);
  else if (P == 2) launch_all<2>(data, W0,b0, W1,b1, W2,b2, W3,b3, W4,b4, out, q, stream);
  else             launch_all<1>(data, W0,b0, W1,b1, W2,b2, W3,b3, W4,b4, out, q, stream);
}